// Round 1
// baseline (283.878 us; speedup 1.0000x reference)
//
#include <hip/hip_runtime.h>
#include <hip/hip_bf16.h>

#define BATCH 512
#define NUM_CLASSES 100000
#define NVEC (NUM_CLASSES / 4)     // 25000 float4 per row
#define BLOCK 512

// cos(0.5), sin(0.5) as literals (margin = 0.5)
#define COS_M 0.8775825618903728f
#define SIN_M 0.479425538604203f
#define SHIFT 64.0f                // fixed logsumexp shift; logits bounded by 63.36

__device__ __forceinline__ float block_reduce_sum(float v) {
    // wave-64 shuffle reduce
    #pragma unroll
    for (int off = 32; off > 0; off >>= 1)
        v += __shfl_down(v, off, 64);
    __shared__ float smem[BLOCK / 64];
    const int lane = threadIdx.x & 63;
    const int wid  = threadIdx.x >> 6;
    if (lane == 0) smem[wid] = v;
    __syncthreads();
    if (wid == 0) {
        v = (lane < (BLOCK / 64)) ? smem[lane] : 0.0f;
        #pragma unroll
        for (int off = 4; off > 0; off >>= 1)
            v += __shfl_down(v, off, 64);
    }
    return v;   // valid in thread 0
}

__global__ __launch_bounds__(BLOCK)
void arc_row_lse(const float* __restrict__ costh,
                 const int*   __restrict__ label,
                 float*       __restrict__ partial) {
    const int row = blockIdx.x;
    const float* rp = costh + (size_t)row * NUM_CLASSES;
    const float4* vp = (const float4*)rp;

    float sum = 0.0f;
    for (int i = threadIdx.x; i < NVEC; i += BLOCK) {
        float4 v = vp[i];
        sum += __expf(fmaf(64.0f, v.x, -SHIFT));
        sum += __expf(fmaf(64.0f, v.y, -SHIFT));
        sum += __expf(fmaf(64.0f, v.z, -SHIFT));
        sum += __expf(fmaf(64.0f, v.w, -SHIFT));
    }

    float tot = block_reduce_sum(sum);

    if (threadIdx.x == 0) {
        const int lab = label[row];
        const float c_y = rp[lab];
        // cos(acos(c) + m) = c*cos(m) - sqrt(1-c^2)*sin(m)
        const float t = 64.0f * (c_y * COS_M -
                                 sqrtf(fmaxf(0.0f, 1.0f - c_y * c_y)) * SIN_M);
        // swap the raw label logit for the margin-shifted one
        const float s = tot - __expf(fmaf(64.0f, c_y, -SHIFT)) + __expf(t - SHIFT);
        // lse - target_logit
        partial[row] = (SHIFT + logf(s)) - t;
    }
}

__global__ __launch_bounds__(BLOCK)
void arc_final_reduce(const float* __restrict__ partial,
                      float*       __restrict__ out) {
    float v = partial[threadIdx.x];   // BLOCK == BATCH == 512
    float tot = block_reduce_sum(v);
    if (threadIdx.x == 0)
        out[0] = tot * (1.0f / (float)BATCH);
}

extern "C" void kernel_launch(void* const* d_in, const int* in_sizes, int n_in,
                              void* d_out, int out_size, void* d_ws, size_t ws_size,
                              hipStream_t stream) {
    const float* costh = (const float*)d_in[0];
    const int*   label = (const int*)d_in[1];
    float* out = (float*)d_out;
    float* partial = (float*)d_ws;   // 512 floats

    arc_row_lse<<<BATCH, BLOCK, 0, stream>>>(costh, label, partial);
    arc_final_reduce<<<1, BLOCK, 0, stream>>>(partial, out);
}